// Round 10
// baseline (6801.974 us; speedup 1.0000x reference)
//
#include <hip/hip_runtime.h>

// ---------------- problem constants ----------------
constexpr int cN  = 50000;
constexpr int cE  = 800000;
constexpr int cEU = 400000;
constexpr int cL2 = 131072;
constexpr int cEL = 1048576;
constexpr int cG  = 512;
constexpr int cH  = 128;
constexpr int cNH = 4;
constexpr int cNL = 2;

// CSR capacities. deg ~ Poisson(16) for GCN1, Poisson(8) for GCN2.
constexpr int CAP1 = 64;
constexpr int CAP2 = 48;

// encoder geometry — ESETS=8 (48 rows = 3 M-tiles, zero pad), ONE 1024-thread
// block = 16 waves/CU. R8/R9 lesson: per-wave VGPR alloc quantum uses TOTAL
// (arch+accum); two 512-thr blocks need total<=128 which forces arch<=64 ->
// spill. A 1024-thr workgroup REQUIRES total<=128 for launchability, so the
// compiler enforces it and 16 waves/CU happen by construction.
constexpr int ESETS = 8;          // sets per encoder block
constexpr int ERT   = ESETS * 6;  // 48 token rows = 3 M-tiles of 16
constexpr int QS    = 388;        // fp32 QKV LDS stride (388 % 32 == 4)
constexpr int AS    = 264;        // bf16 A LDS stride

// dynamic LDS layout (bytes)
constexpr int OFF_QKV = 0;                        // 48*388*4 = 74496
constexpr int OFF_AH  = 74496;                    // 48*264*2 = 25344
constexpr int OFF_AL  = OFF_AH + 25344;           // 99840
constexpr int OFF_ATT = OFF_AL + 25344;           // 125184 ; 8*144*4 = 4608
constexpr int OFF_IDX = OFF_ATT + 4608;           // 129792 ; 48 ints = 192
constexpr int SMEM_SZ = OFF_IDX + 192;            // 129,984 B (1 block/CU)

typedef __attribute__((ext_vector_type(8))) short short8v;
typedef __attribute__((ext_vector_type(4))) float f32x4;

#define DEVI __device__ __forceinline__

DEVI unsigned fmap(float x) {
  unsigned u = __float_as_uint(x);
  return (u & 0x80000000u) ? ~u : (u | 0x80000000u);
}
DEVI float funmap(unsigned m) {
  return __uint_as_float((m & 0x80000000u) ? (m & 0x7FFFFFFFu) : ~m);
}
DEVI float gelu_exact(float x) {
  return 0.5f * x * (1.0f + erff(x * 0.70710678118654752f));
}
DEVI unsigned short f2b_rn(float x) {            // fp32 -> bf16 round-nearest-even
  unsigned u = __float_as_uint(x);
  return (unsigned short)((u + 0x7FFFu + ((u >> 16) & 1u)) >> 16);
}
DEVI float b2f(unsigned short h) { return __uint_as_float(((unsigned)h) << 16); }
// packed split writes: 2 consecutive cols -> one b32 per array (idx must be even)
DEVI void sp2(unsigned short* hi, unsigned short* lo, int idx, float a0, float a1) {
  unsigned short h0 = f2b_rn(a0), h1 = f2b_rn(a1);
  unsigned short l0 = f2b_rn(a0 - b2f(h0)), l1 = f2b_rn(a1 - b2f(h1));
  *(unsigned*)&hi[idx] = (unsigned)h0 | ((unsigned)h1 << 16);
  *(unsigned*)&lo[idx] = (unsigned)l0 | ((unsigned)l1 << 16);
}
// 4 consecutive cols -> one b64 per array (idx must be multiple of 4)
DEVI void sp4(unsigned short* hi, unsigned short* lo, int idx, float4 v) {
  unsigned short h0 = f2b_rn(v.x), h1 = f2b_rn(v.y), h2 = f2b_rn(v.z), h3 = f2b_rn(v.w);
  unsigned short l0 = f2b_rn(v.x - b2f(h0)), l1 = f2b_rn(v.y - b2f(h1));
  unsigned short l2 = f2b_rn(v.z - b2f(h2)), l3 = f2b_rn(v.w - b2f(h3));
  uint2 H, L;
  H.x = (unsigned)h0 | ((unsigned)h1 << 16);
  H.y = (unsigned)h2 | ((unsigned)h3 << 16);
  L.x = (unsigned)l0 | ((unsigned)l1 << 16);
  L.y = (unsigned)l2 | ((unsigned)l3 << 16);
  *(uint2*)&hi[idx] = H;
  *(uint2*)&lo[idx] = L;
}

// split-bf16 GEMM micro-tile: MCNT M-tiles (16 rows apart in A), NKS K-steps.
// acc[mi] = sum over ks of (ahi*bhi + ahi*blo + alo*bhi), 3 independent chains.
template<int MCNT, int NKS>
DEVI void mfma_gemm(const unsigned short* __restrict__ Ahs,
                    const unsigned short* __restrict__ Als,
                    int abase,
                    const unsigned short* __restrict__ wp,
                    const unsigned short* __restrict__ wq,
                    f32x4* acc) {
  f32x4 aH[MCNT], a1[MCNT], a2[MCNT];
  #pragma unroll
  for (int mi = 0; mi < MCNT; ++mi) {
    aH[mi] = (f32x4){0.f, 0.f, 0.f, 0.f};
    a1[mi] = (f32x4){0.f, 0.f, 0.f, 0.f};
    a2[mi] = (f32x4){0.f, 0.f, 0.f, 0.f};
  }
  #pragma unroll
  for (int ks = 0; ks < NKS; ++ks) {
    short8v bh = *(const short8v*)&wp[ks * 32];
    short8v bl = *(const short8v*)&wq[ks * 32];
    #pragma unroll
    for (int mi = 0; mi < MCNT; ++mi) {
      int ao = abase + mi * (16 * AS) + ks * 32;
      short8v ah = *(const short8v*)&Ahs[ao];
      short8v al = *(const short8v*)&Als[ao];
      a1[mi] = __builtin_amdgcn_mfma_f32_16x16x32_bf16(al, bh, a1[mi], 0, 0, 0);
      a2[mi] = __builtin_amdgcn_mfma_f32_16x16x32_bf16(ah, bl, a2[mi], 0, 0, 0);
      aH[mi] = __builtin_amdgcn_mfma_f32_16x16x32_bf16(ah, bh, aH[mi], 0, 0, 0);
    }
  }
  #pragma unroll
  for (int mi = 0; mi < MCNT; ++mi) {
    #pragma unroll
    for (int j = 0; j < 4; ++j) acc[mi][j] = aH[mi][j] + (a1[mi][j] + a2[mi][j]);
  }
}

// ---------------- tiny utility kernels ----------------
__global__ void fill_k(float* p, float v, int n) {
  int i = blockIdx.x * 256 + threadIdx.x;
  if (i < n) p[i] = v;
}

// dinv from CSR counts: degree = cnt (edges) + 1 (self loop)
__global__ void cnt_to_dinv_k(const int* __restrict__ cnt, float* __restrict__ dinv, int n) {
  int i = blockIdx.x * 256 + threadIdx.x;
  if (i < n) dinv[i] = rsqrtf((float)cnt[i] + 1.0f);
}

// bucket edges by destination into fixed-capacity CSR (1 int atomic / edge)
__global__ void csr_fill_k(const int* __restrict__ ei, int* __restrict__ cnt,
                           int* __restrict__ csr, int cap, int nE) {
  int e = blockIdx.x * 256 + threadIdx.x;
  if (e >= nE) return;
  int s = ei[e], d = ei[nE + e];
  int slot = atomicAdd(&cnt[d], 1);
  if (slot < cap) csr[(long)d * cap + slot] = s;
}

// split fp32 weights into bf16 hi/lo (error-compensated MFMA operands)
__global__ void split_w_k(const float* __restrict__ src, unsigned short* __restrict__ hi,
                          unsigned short* __restrict__ lo, int n) {
  int i = blockIdx.x * 256 + threadIdx.x;
  if (i < n) {
    float x = src[i];
    unsigned short h = f2b_rn(x);
    hi[i] = h;
    lo[i] = f2b_rn(x - b2f(h));
  }
}

// ---------------- generic C[M,128] = A[M,128] @ W[128,128]^T ----------------
__global__ __launch_bounds__(256) void gemm128_k(const float* __restrict__ A,
                                                 const float* __restrict__ W,
                                                 float* __restrict__ C, int M) {
  __shared__ float At[16][132];
  int c = threadIdx.x & 127, rr = threadIdx.x >> 7;
  int base = blockIdx.x * 128;
  for (int tile = 0; tile < 8; ++tile) {
    int r0 = base + tile * 16;
    if (r0 >= M) break;
    __syncthreads();
    for (int i = threadIdx.x; i < 16 * 32; i += 256) {
      int r = i >> 5, s4 = (i & 31) * 4;
      if (r0 + r < M) *(float4*)&At[r][s4] = *(const float4*)&A[(long)(r0 + r) * cH + s4];
    }
    __syncthreads();
    float acc[8];
    #pragma unroll
    for (int j = 0; j < 8; ++j) acc[j] = 0.f;
    const float* wr = W + (long)c * cH;
    for (int k = 0; k < cH; k += 4) {
      float4 w4 = *(const float4*)(wr + k);
      #pragma unroll
      for (int j = 0; j < 8; ++j) {
        float4 a4 = *(const float4*)&At[rr * 8 + j][k];
        acc[j] = fmaf(a4.x, w4.x, acc[j]);
        acc[j] = fmaf(a4.y, w4.y, acc[j]);
        acc[j] = fmaf(a4.z, w4.z, acc[j]);
        acc[j] = fmaf(a4.w, w4.w, acc[j]);
      }
    }
    #pragma unroll
    for (int j = 0; j < 8; ++j) {
      int r = r0 + rr * 8 + j;
      if (r < M) C[(long)r * cH + c] = acc[j];
    }
  }
}

// ---------------- GCN aggregation, gather form (NO column atomics) ----------------
template<int STORE>
__global__ __launch_bounds__(256) void gcn_gather_k(
    const float* __restrict__ xw, const float* __restrict__ dinv,
    const int* __restrict__ csr, const int* __restrict__ cnt,
    const float* __restrict__ bias, float* __restrict__ out,
    const int* __restrict__ gidx,
    float* __restrict__ sum, unsigned* __restrict__ mx, unsigned* __restrict__ mn,
    float* __restrict__ ccnt, int n, int cap) {
  int wv = threadIdx.x >> 6, lane = threadIdx.x & 63;
  int r = blockIdx.x * 4 + wv;
  if (r >= n) return;
  int c = lane * 2;
  float di = dinv[r];
  float2 v0 = *(const float2*)&xw[(long)r * cH + c];
  float2 b2 = *(const float2*)&bias[c];
  float a0 = b2.x + di * di * v0.x;
  float a1 = b2.y + di * di * v0.y;
  int deg = cnt[r];
  if (deg > cap) deg = cap;
  long base = (long)r * cap;
  for (int k = 0; k < deg; ++k) {
    int s = csr[base + k];                      // wave-uniform -> scalar load
    float w = dinv[s] * di;
    float2 v = *(const float2*)&xw[(long)s * cH + c];
    a0 = fmaf(w, v.x, a0);
    a1 = fmaf(w, v.y, a1);
  }
  if (STORE) {
    float2 o; o.x = a0; o.y = a1;
    *(float2*)&out[(long)r * cH + c] = o;
  } else {
    a0 = fmaxf(a0, 0.f);
    a1 = fmaxf(a1, 0.f);
    int g = gidx[r];
    long b = (long)g * cH + c;
    atomicAdd(&sum[b + 0], a0); atomicAdd(&sum[b + 1], a1);
    atomicMax(&mx[b + 0], fmap(a0)); atomicMax(&mx[b + 1], fmap(a1));
    atomicMin(&mn[b + 0], fmap(a0)); atomicMin(&mn[b + 1], fmap(a1));
    if (lane == 0) atomicAdd(&ccnt[g], 1.0f);
  }
}

// ---------------- fused 2-layer transformer encoder (MFMA split-bf16) ----------------
// 8 sets x 6 tokens = 48 rows = 3 M-tiles. ONE 1024-thread block (16 waves).
// Wave w = (mg, cw): mg = w>>3 picks M-tiles (mg0: m=0,1; mg1: m=2), cw = w&7
// picks column tiles. Per-wave MFMA work halves vs the 512-thread version;
// 4 waves/SIMD hide MFMA+LDS latency chains.
__global__ __launch_bounds__(1024, 1) void encoder_k(
    const float* __restrict__ H0, const float* __restrict__ EA,
    const float* __restrict__ LEW, const float* __restrict__ LEB,
    const int* __restrict__ ue, const int* __restrict__ l2nm,
    const int* __restrict__ batch,
    const unsigned short* __restrict__ WinH, const unsigned short* __restrict__ WinL,
    const float* __restrict__ Bin,
    const unsigned short* __restrict__ WoutH, const unsigned short* __restrict__ WoutL,
    const float* __restrict__ Bout,
    const float* __restrict__ Ln1g, const float* __restrict__ Ln1b,
    const float* __restrict__ Ln2g, const float* __restrict__ Ln2b,
    const unsigned short* __restrict__ Wf1H, const unsigned short* __restrict__ Wf1L,
    const float* __restrict__ Bf1,
    const unsigned short* __restrict__ Wf2H, const unsigned short* __restrict__ Wf2L,
    const float* __restrict__ Bf2,
    float* __restrict__ H1,
    float* __restrict__ sum1, unsigned* __restrict__ mx1, unsigned* __restrict__ mn1,
    float* __restrict__ cnt1, int* __restrict__ l2b) {
  extern __shared__ char smem[];
  float* QKV = (float*)(smem + OFF_QKV);               // [48][388] fp32
  unsigned short* Ahs = (unsigned short*)(smem + OFF_AH); // [48][264] bf16 hi
  unsigned short* Als = (unsigned short*)(smem + OFF_AL); // [48][264] bf16 lo
  float* att = (float*)(smem + OFF_ATT);               // [8][144]
  int* nidx = (int*)(smem + OFF_IDX);                  // 32 node ids
  int* eidx = nidx + 32;                               // 16 edge ids

  const int tid = threadIdx.x;
  const int lane = tid & 63, wv = tid >> 6;
  const int lr = lane & 15, lq = lane >> 4;
  const int cw = wv & 7, mg = wv >> 3;     // column-wave, M-group
  const int base = blockIdx.x * ESETS;

  if (tid < ESETS) {
    int e = l2nm[base + tid];
    int f = l2nm[cL2 + base + tid];
    eidx[tid * 2 + 0] = e;
    eidx[tid * 2 + 1] = f;
    nidx[tid * 4 + 0] = ue[e];
    nidx[tid * 4 + 1] = ue[cEU + e];
    nidx[tid * 4 + 2] = ue[f];
    nidx[tid * 4 + 3] = ue[cEU + f];
  }
  __syncthreads();
  // H0 rows (4 per set) -> A hi/lo: 32 nodes x 32 float4 = 1024 items
  {
    int i = tid;
    int q = i >> 5, s4 = (i & 31) * 4;
    int r = (q >> 2) * 6 + (q & 3);
    float4 v = *(const float4*)&H0[(long)nidx[q] * cH + s4];
    sp4(Ahs, Als, r * AS + s4, v);
  }
  // edge rows (2 per set): EA[e] @ LEW^T + LEB; 16 rows x 64 pairs = 1024 items
  {
    int i = tid;
    int c = (i & 63) * 2, q = i >> 6;
    const float* row = EA + (long)eidx[q] * 16;
    const float* w0 = LEW + c * 16;
    const float* w1 = LEW + (c + 1) * 16;
    float2 bb2 = *(const float2*)&LEB[c];
    float a0 = bb2.x, a1 = bb2.y;
    #pragma unroll
    for (int d = 0; d < 16; ++d) {
      float rv = row[d];
      a0 = fmaf(rv, w0[d], a0);
      a1 = fmaf(rv, w1[d], a1);
    }
    int r = (q >> 1) * 6 + 4 + (q & 1);
    sp2(Ahs, Als, r * AS + c, a0, a1);
  }
  __syncthreads();

  for (int l = 0; l < cNL; ++l) {
    // ---- qkv: [48,128] @ Win^T -> QKV fp32 [48][0..384) ----
    {
      const unsigned short* WH = WinH + (long)l * 384 * 128;
      const unsigned short* WL = WinL + (long)l * 384 * 128;
      const float* BB = Bin + l * 384;
      #pragma unroll
      for (int ni = 0; ni < 3; ++ni) {
        int col = (cw + 8 * ni) * 16 + lr;
        const unsigned short* wp = WH + (long)col * 128 + (lq << 3);
        const unsigned short* wq = WL + (long)col * 128 + (lq << 3);
        float bv = BB[col];
        if (mg == 0) {
          f32x4 acc[2];
          mfma_gemm<2, 4>(Ahs, Als, lr * AS + (lq << 3), wp, wq, acc);
          #pragma unroll
          for (int mi = 0; mi < 2; ++mi) {
            int r0 = mi * 16 + (lq << 2);
            #pragma unroll
            for (int j = 0; j < 4; ++j) QKV[(r0 + j) * QS + col] = acc[mi][j] + bv;
          }
        } else {
          f32x4 acc[1];
          mfma_gemm<1, 4>(Ahs, Als, (32 + lr) * AS + (lq << 3), wp, wq, acc);
          int r0 = 32 + (lq << 2);
          #pragma unroll
          for (int j = 0; j < 4; ++j) QKV[(r0 + j) * QS + col] = acc[0][j] + bv;
        }
      }
    }
    __syncthreads();
    // ---- attention scores: wave pair (s, s+8) covers set s, 2 heads each ----
    {
      const int s = cw;
      float* attS = att + s * 144;
      if (lane < 12) {
        int h = mg * 2 + lane / 6, qt = lane % 6;
        const float* qp = &QKV[(s * 6 + qt) * QS + h * 32];
        float4 qv[8];
        #pragma unroll
        for (int j4 = 0; j4 < 8; ++j4) qv[j4] = *(const float4*)&qp[j4 * 4];
        float sc[6];
        #pragma unroll
        for (int kt = 0; kt < 6; ++kt) {
          const float* kp = &QKV[(s * 6 + kt) * QS + 128 + h * 32];
          float d = 0.f;
          #pragma unroll
          for (int j4 = 0; j4 < 8; ++j4) {
            float4 b4 = *(const float4*)&kp[j4 * 4];
            d = fmaf(qv[j4].x, b4.x, d); d = fmaf(qv[j4].y, b4.y, d);
            d = fmaf(qv[j4].z, b4.z, d); d = fmaf(qv[j4].w, b4.w, d);
          }
          sc[kt] = d * 0.17677669529663687f;   // 1/sqrt(32)
        }
        float mx = sc[0];
        #pragma unroll
        for (int kt = 1; kt < 6; ++kt) mx = fmaxf(mx, sc[kt]);
        float ev[6]; float sum = 0.f;
        #pragma unroll
        for (int kt = 0; kt < 6; ++kt) { ev[kt] = expf(sc[kt] - mx); sum += ev[kt]; }
        float inv = 1.f / sum;
        #pragma unroll
        for (int kt = 0; kt < 6; ++kt) attS[(h * 6 + qt) * 6 + kt] = ev[kt] * inv;
      }
    }
    __syncthreads();
    // ---- AV: wave pair splits set's 6 rows (3 each); 2 cols/lane ----
    {
      const int s = cw;
      float* attS = att + s * 144;
      int c = lane * 2;
      int h = c >> 5;
      #pragma unroll
      for (int ri = 0; ri < 3; ++ri) {
        int r = mg * 3 + ri;
        const float* arow = &attS[(h * 6 + r) * 6];
        float d0 = 0.f, d1 = 0.f;
        #pragma unroll
        for (int kt = 0; kt < 6; ++kt) {
          float2 v2 = *(const float2*)&QKV[(s * 6 + kt) * QS + 256 + c];
          float a = arow[kt];
          d0 = fmaf(a, v2.x, d0);
          d1 = fmaf(a, v2.y, d1);
        }
        sp2(Ahs, Als, (s * 6 + r) * AS + 128 + c, d0, d1);
      }
    }
    __syncthreads();
    // ---- out-proj: A[.][128..256) @ Wout^T -> QKV fp32 [.][0..128) ----
    {
      const unsigned short* WH = WoutH + (long)l * 128 * 128;
      const unsigned short* WL = WoutL + (long)l * 128 * 128;
      int col = cw * 16 + lr;
      const unsigned short* wp = WH + (long)col * 128 + (lq << 3);
      const unsigned short* wq = WL + (long)col * 128 + (lq << 3);
      float bv = Bout[l * 128 + col];
      if (mg == 0) {
        f32x4 acc[2];
        mfma_gemm<2, 4>(Ahs, Als, lr * AS + 128 + (lq << 3), wp, wq, acc);
        #pragma unroll
        for (int mi = 0; mi < 2; ++mi) {
          int r0 = mi * 16 + (lq << 2);
          #pragma unroll
          for (int j = 0; j < 4; ++j) QKV[(r0 + j) * QS + col] = acc[mi][j] + bv;
        }
      } else {
        f32x4 acc[1];
        mfma_gemm<1, 4>(Ahs, Als, (32 + lr) * AS + 128 + (lq << 3), wp, wq, acc);
        int r0 = 32 + (lq << 2);
        #pragma unroll
        for (int j = 0; j < 4; ++j) QKV[(r0 + j) * QS + col] = acc[0][j] + bv;
      }
    }
    __syncthreads();
    // ---- residual + LN1 (packed): 1024 thr, 32 rows/pass, 2 passes ----
    {
      const float* gg = Ln1g + l * cH;
      const float* bb = Ln1b + l * cH;
      #pragma unroll
      for (int p = 0; p < 2; ++p) {
        int r = p * 32 + (tid >> 5);
        if (r < ERT) {
          int c0 = (tid & 31) * 4;
          ushort4 ah4 = *(const ushort4*)&Ahs[r * AS + c0];
          ushort4 al4 = *(const ushort4*)&Als[r * AS + c0];
          float4 q4 = *(const float4*)&QKV[r * QS + c0];
          float y[4];
          y[0] = b2f(ah4.x) + b2f(al4.x) + q4.x;
          y[1] = b2f(ah4.y) + b2f(al4.y) + q4.y;
          y[2] = b2f(ah4.z) + b2f(al4.z) + q4.z;
          y[3] = b2f(ah4.w) + b2f(al4.w) + q4.w;
          float s = 0.f, s2 = 0.f;
          #pragma unroll
          for (int j = 0; j < 4; ++j) { s += y[j]; s2 += y[j] * y[j]; }
          #pragma unroll
          for (int m = 1; m < 32; m <<= 1) { s += __shfl_xor(s, m, 32); s2 += __shfl_xor(s2, m, 32); }
          float mean = s * (1.f / 128.f);
          float rstd = rsqrtf(s2 * (1.f / 128.f) - mean * mean + 1e-5f);
          float4 g4 = *(const float4*)&gg[c0];
          float4 b4v = *(const float4*)&bb[c0];
          float4 xn4;
          xn4.x = (y[0] - mean) * rstd * g4.x + b4v.x;
          xn4.y = (y[1] - mean) * rstd * g4.y + b4v.y;
          xn4.z = (y[2] - mean) * rstd * g4.z + b4v.z;
          xn4.w = (y[3] - mean) * rstd * g4.w + b4v.w;
          *(float4*)&QKV[r * QS + 128 + c0] = xn4;   // residual master for LN2
          sp4(Ahs, Als, r * AS + c0, xn4);           // A operand for ff1
        }
      }
    }
    __syncthreads();
    // ---- ff1: A[0..128) @ Wf1^T (N=256) -> raw acc into FREE QKV cols ----
    // free fp32 LDS cols: [0..128) and [256..384); [128..256) is live LN1.
    {
      const unsigned short* WH = Wf1H + (long)l * 256 * 128;
      const unsigned short* WL = Wf1L + (long)l * 256 * 128;
      #pragma unroll
      for (int ni = 0; ni < 2; ++ni) {
        int col = (cw + 8 * ni) * 16 + lr;
        const unsigned short* wp = WH + (long)col * 128 + (lq << 3);
        const unsigned short* wq = WL + (long)col * 128 + (lq << 3);
        int lc = col + (col >= 128 ? 128 : 0);   // map into free cols
        if (mg == 0) {
          f32x4 acc[2];
          mfma_gemm<2, 4>(Ahs, Als, lr * AS + (lq << 3), wp, wq, acc);
          #pragma unroll
          for (int mi = 0; mi < 2; ++mi) {
            int r0 = mi * 16 + (lq << 2);
            #pragma unroll
            for (int j = 0; j < 4; ++j) QKV[(r0 + j) * QS + lc] = acc[mi][j];
          }
        } else {
          f32x4 acc[1];
          mfma_gemm<1, 4>(Ahs, Als, (32 + lr) * AS + (lq << 3), wp, wq, acc);
          int r0 = 32 + (lq << 2);
          #pragma unroll
          for (int j = 0; j < 4; ++j) QKV[(r0 + j) * QS + lc] = acc[0][j];
        }
      }
    }
    __syncthreads();   // ff1 acc written; A reads done
    // ---- relu + bias + split (packed): QKV free cols -> A hi/lo [0..256) ----
    for (int i = tid; i < ERT * 128; i += 1024) {
      int r = i >> 7, n = (i & 127) * 2;
      int lc = n + (n >= 128 ? 128 : 0);
      float2 v2 = *(const float2*)&QKV[r * QS + lc];
      float2 bb2 = *(const float2*)&Bf1[l * 256 + n];
      float h0 = fmaxf(v2.x + bb2.x, 0.f);
      float h1 = fmaxf(v2.y + bb2.y, 0.f);
      sp2(Ahs, Als, r * AS + n, h0, h1);
    }
    __syncthreads();
    // ---- ff2: A[0..256) @ Wf2^T (K=256) -> QKV fp32 [0..128) ----
    {
      const unsigned short* WH = Wf2H + (long)l * 128 * 256;
      const unsigned short* WL = Wf2L + (long)l * 128 * 256;
      int col = cw * 16 + lr;
      const unsigned short* wp = WH + (long)col * 256 + (lq << 3);
      const unsigned short* wq = WL + (long)col * 256 + (lq << 3);
      float bv = Bf2[l * 128 + col];
      if (mg == 0) {
        f32x4 acc[2];
        mfma_gemm<2, 8>(Ahs, Als, lr * AS + (lq << 3), wp, wq, acc);
        #pragma unroll
        for (int mi = 0; mi < 2; ++mi) {
          int r0 = mi * 16 + (lq << 2);
          #pragma unroll
          for (int j = 0; j < 4; ++j) QKV[(r0 + j) * QS + col] = acc[mi][j] + bv;
        }
      } else {
        f32x4 acc[1];
        mfma_gemm<1, 8>(Ahs, Als, (32 + lr) * AS + (lq << 3), wp, wq, acc);
        int r0 = 32 + (lq << 2);
        #pragma unroll
        for (int j = 0; j < 4; ++j) QKV[(r0 + j) * QS + col] = acc[0][j] + bv;
      }
    }
    __syncthreads();
    // ---- residual + LN2 (packed): QKV[128..256) + QKV[0..128) -> A hi/lo ----
    {
      const float* gg = Ln2g + l * cH;
      const float* bb = Ln2b + l * cH;
      #pragma unroll
      for (int p = 0; p < 2; ++p) {
        int r = p * 32 + (tid >> 5);
        if (r < ERT) {
          int c0 = (tid & 31) * 4;
          float4 qa = *(const float4*)&QKV[r * QS + 128 + c0];
          float4 qb = *(const float4*)&QKV[r * QS + c0];
          float y[4];
          y[0] = qa.x + qb.x; y[1] = qa.y + qb.y;
          y[2] = qa.z + qb.z; y[3] = qa.w + qb.w;
          float s = 0.f, s2 = 0.f;
          #pragma unroll
          for (int j = 0; j < 4; ++j) { s += y[j]; s2 += y[j] * y[j]; }
          #pragma unroll
          for (int m = 1; m < 32; m <<= 1) { s += __shfl_xor(s, m, 32); s2 += __shfl_xor(s2, m, 32); }
          float mean = s * (1.f / 128.f);
          float rstd = rsqrtf(s2 * (1.f / 128.f) - mean * mean + 1e-5f);
          float4 g4 = *(const float4*)&gg[c0];
          float4 b4v = *(const float4*)&bb[c0];
          float4 xn4;
          xn4.x = (y[0] - mean) * rstd * g4.x + b4v.x;
          xn4.y = (y[1] - mean) * rstd * g4.y + b4v.y;
          xn4.z = (y[2] - mean) * rstd * g4.z + b4v.z;
          xn4.w = (y[3] - mean) * rstd * g4.w + b4v.w;
          sp4(Ahs, Als, r * AS + c0, xn4);
        }
      }
    }
    __syncthreads();
  }

  // ---- epilogue: H1 = mean over 6 tokens; fused H1 pooling + L2B (packed) ----
  if (tid < ESETS * 64) {                      // 512 threads: 8 sets x 64 pairs
    int s = tid >> 6, c = (tid & 63) * 2;
    float m0 = 0.f, m1 = 0.f;
    #pragma unroll
    for (int t = 0; t < 6; ++t) {
      unsigned hh = *(const unsigned*)&Ahs[(s * 6 + t) * AS + c];
      unsigned ll = *(const unsigned*)&Als[(s * 6 + t) * AS + c];
      m0 += b2f((unsigned short)(hh & 0xFFFFu)) + b2f((unsigned short)(ll & 0xFFFFu));
      m1 += b2f((unsigned short)(hh >> 16)) + b2f((unsigned short)(ll >> 16));
    }
    float v0 = m0 * (1.f / 6.f), v1 = m1 * (1.f / 6.f);
    float2 o; o.x = v0; o.y = v1;
    *(float2*)&H1[(long)(base + s) * cH + c] = o;
    int g = batch[nidx[s * 4]];               // l2_batch = batch[ue0[l2nm0]]
    long b = (long)g * cH + c;
    atomicAdd(&sum1[b + 0], v0);  atomicAdd(&sum1[b + 1], v1);
    atomicMax(&mx1[b + 0], fmap(v0)); atomicMax(&mx1[b + 1], fmap(v1));
    atomicMin(&mn1[b + 0], fmap(v0)); atomicMin(&mn1[b + 1], fmap(v1));
    if (c == 0) {
      atomicAdd(&cnt1[g], 1.0f);
      l2b[base + s] = g;
    }
  }
}

// ---------------- pooling ----------------
// init all 3 stat sets in one dispatch
__global__ void init_stats3_k(char* ST, size_t stride) {
  int i = blockIdx.x * 256 + threadIdx.x;
  if (i >= cG * cH) return;
  #pragma unroll
  for (int p = 0; p < 3; ++p) {
    char* b = ST + (size_t)p * stride;
    ((float*)b)[i] = 0.f;
    ((unsigned*)(b + (size_t)cG * cH * 4))[i] = 0u;
    ((unsigned*)(b + (size_t)cG * cH * 8))[i] = 0xFFFFFFFFu;
    if (i < cG) ((float*)(b + (size_t)cG * cH * 12))[i] = 0.f;
  }
}

// segmented pool over SORTED group index (batch): ~8x fewer atomics
__global__ void pool_sorted_k(const float* __restrict__ X, const int* __restrict__ gidx,
                              float* sum, unsigned* mx, unsigned* mn, float* cnt, int n) {
  long t = (long)blockIdx.x * 256 + threadIdx.x;
  int q = (int)(t & 31) * 4;
  long r0 = (t >> 5) * 8;
  if (r0 >= n) return;
  int gcur = -1;
  float s0 = 0, s1 = 0, s2 = 0, s3 = 0, cc = 0;
  float x0 = 0, x1 = 0, x2 = 0, x3 = 0;
  float n0 = 0, n1 = 0, n2 = 0, n3 = 0;
  for (int k = 0; k < 8; ++k) {
    long r = r0 + k;
    if (r >= n) break;
    int g = gidx[r];
    float4 v = *(const float4*)&X[r * cH + q];
    if (g != gcur) {
      if (gcur >= 0) {
        long b = (long)gcur * cH + q;
        atomicAdd(&sum[b + 0], s0); atomicAdd(&sum[b + 1], s1);
        atomicAdd(&sum[b + 2], s2); atomicAdd(&sum[b + 3], s3);
        atomicMax(&mx[b + 0], fmap(x0)); atomicMax(&mx[b + 1], fmap(x1));
        atomicMax(&mx[b + 2], fmap(x2)); atomicMax(&mx[b + 3], fmap(x3));
        atomicMin(&mn[b + 0], fmap(n0)); atomicMin(&mn[b + 1], fmap(n1));
        atomicMin(&mn[b + 2], fmap(n2)); atomicMin(&mn[b + 3], fmap(n3));
        if (q == 0) atomicAdd(&cnt[gcur], cc);
      }
      gcur = g;
      s0 = v.x; s1 = v.y; s2 = v.z; s3 = v.w;
      x0 = v.x; x1 = v.y; x2 = v.z; x3 = v.w;
      n0 = v.x; n1 = v.y; n2 = v.z; n3 = v.w;
      cc = 1.f;
    } else {
      s0 += v.x; s1 += v.y; s2 += v.z; s3 += v.w;
      x0 = fmaxf(x0, v.x); x1 = fmaxf(x1, v.y); x2 = fmaxf(x2, v.z); x3 = fmaxf(x3, v.w);
      n0 = fminf(n0, v.x); n1 = fminf(n1, v.y); n2 = fminf(n2, v.z); n3 = fminf(n3, v.w);
      cc += 1.f;
    }
  }
  if (gcur >= 0) {
    long b = (long)gcur * cH + q;
    atomicAdd(&sum[b + 0], s0); atomicAdd(&sum[b + 1], s1);
    atomicAdd(&sum[b + 2], s2); atomicAdd(&sum[b + 3], s3);
    atomicMax(&mx[b + 0], fmap(x0)); atomicMax(&mx[b + 1], fmap(x1));
    atomicMax(&mx[b + 2], fmap(x2)); atomicMax(&mx[b + 3], fmap(x3));
    atomicMin(&mn[b + 0], fmap(n0)); atomicMin(&mn[b + 1], fmap(n1));
    atomicMin(&mn[b + 2], fmap(n2)); atomicMin(&mn[b + 3], fmap(n3));
    if (q == 0) atomicAdd(&cnt[gcur], cc);
  }
}

// ---------------- final MLP per graph (builds pooled vector from stats) ----------------
__global__ __launch_bounds__(128) void mlp_k(
    const char* __restrict__ ST, size_t stride,
    const float* __restrict__ f0w, const float* __restrict__ f0b,
    const float* __restrict__ f0g, const float* __restrict__ f0bb,
    const float* __restrict__ f1w, const float* __restrict__ f1b,
    const float* __restrict__ f1g, const float* __restrict__ f1bb,
    const float* __restrict__ fow, const float* __restrict__ fob,
    float* __restrict__ out) {
  __shared__ float hin[1152];
  __shared__ float red[8];
  int g = blockIdx.x, tid = threadIdx.x;
  #pragma unroll
  for (int p = 0; p < 3; ++p) {
    const char* b = ST + (size_t)p * stride;
    const float* sum = (const float*)b;
    const unsigned* mx = (const unsigned*)(b + (size_t)cG * cH * 4);
    const unsigned* mn = (const unsigned*)(b + (size_t)cG * cH * 8);
    const float* cnt = (const float*)(b + (size_t)cG * cH * 12);
    int idx = g * cH + tid;
    float ct = cnt[g];
    float mean = sum[idx] / fmaxf(ct, 1.f);
    float mxv = (ct > 0.f) ? funmap(mx[idx]) : 0.f;
    float mnv = (ct > 0.f) ? funmap(mn[idx]) : 0.f;
    hin[p * 384 + tid] = mnv;
    hin[p * 384 + 128 + tid] = mxv;
    hin[p * 384 + 256 + tid] = mean;
  }
  __syncthreads();
  float acc = f0b[tid];
  {
    const float* wr = f0w + (long)tid * 1152;
    for (int k = 0; k < 1152; k += 4) {
      float4 w4 = *(const float4*)(wr + k);
      float4 h4 = *(const float4*)&hin[k];
      acc = fmaf(h4.x, w4.x, acc);
      acc = fmaf(h4.y, w4.y, acc);
      acc = fmaf(h4.z, w4.z, acc);
      acc = fmaf(h4.w, w4.w, acc);
    }
  }
  float s = acc, s2 = acc * acc;
  #pragma unroll
  for (int m = 1; m < 64; m <<= 1) { s += __shfl_xor(s, m); s2 += __shfl_xor(s2, m); }
  if ((tid & 63) == 0) { red[tid >> 6] = s; red[4 + (tid >> 6)] = s2; }
  __syncthreads();
  s = red[0] + red[1]; s2 = red[4] + red[5];
  {
    float mean = s * (1.f / 128.f);
    float rstd = rsqrtf(s2 * (1.f / 128.f) - mean * mean + 1e-5f);
    float xn = (acc - mean) * rstd * f0g[tid] + f0bb[tid];
    float h0 = gelu_exact(xn);
    __syncthreads();
    hin[tid] = h0;
  }
  __syncthreads();
  acc = f1b[tid];
  {
    const float* wr = f1w + (long)tid * 128;
    for (int k = 0; k < 128; k += 4) {
      float4 w4 = *(const float4*)(wr + k);
      float4 h4 = *(const float4*)&hin[k];
      acc = fmaf(h4.x, w4.x, acc);
      acc = fmaf(h4.y, w4.y, acc);
      acc = fmaf(h4.z, w4.z, acc);
      acc = fmaf(h4.w, w4.w, acc);
    }
  }
  s = acc; s2 = acc * acc;
  #pragma unroll
  for (int m = 1; m < 64; m <<= 1) { s += __shfl_xor(s, m); s2 += __shfl_xor(s2, m); }
  __syncthreads();
  if ((tid & 63) == 0) { red[tid >> 6] = s; red[4 + (tid >> 6)] = s2; }
  __syncthreads();
  s = red[0] + red[1]; s2 = red[4] + red[5];
  float h1;
  {
    float mean = s * (1.f / 128.f);
    float rstd = rsqrtf(s2 * (1.f / 128.f) - mean * mean + 1e-5f);
    float xn = (acc - mean) * rstd * f1g[tid] + f1bb[tid];
    h1 = gelu_exact(xn);
  }
  float p = h1 * fow[tid];
  #pragma unroll
  for (int m = 1; m < 64; m <<= 1) p += __shfl_xor(p, m);
  __syncthreads();
  if ((tid & 63) == 0) red[tid >> 6] = p;
  __syncthreads();
  if (tid == 0) out[g] = red[0] + red[1] + fob[0];
}

// ---------------- launcher ----------------
extern "C" void kernel_launch(void* const* d_in, const int* in_sizes, int n_in,
                              void* d_out, int out_size, void* d_ws, size_t ws_size,
                              hipStream_t stream) {
  const float* x     = (const float*)d_in[0];
  const float* ea    = (const float*)d_in[1];
  const int*   ei    = (const int*)d_in[2];
  const int*   ue    = (const int*)d_in[3];
  const int*   batch = (const int*)d_in[4];
  const int*   l2nm  = (const int*)d_in[5];
  const int*   l2ei  = (const int*)d_in[6];
  const float* lew   = (const float*)d_in[8];
  const float* leb   = (const float*)d_in[9];
  const float* g1w   = (const float*)d_in[10];
  const float* g1b   = (const float*)d_in[11];
  const float* g2w   = (const float*)d_in[12];
  const float* g2b   = (const float*)d_in[13];
  const float* tinw  = (const float*)d_in[14];
  const float* tinb  = (const float*)d_in[15];
  const float* toutw = (const float*)d_in[16];
  const float* toutb = (const float*)d_in[17];
  const float* tl1g  = (const float*)d_in[18];
  const float* tl1b  = (const float*)d_in[19];
  const float* tl2g  = (const float*)d_in[20];
  const float* tl2b  = (const float*)d_in[21];
  const float* tf1w  = (const float*)d_in[22];
  const float* tf1b  = (const float*)d_in[23];
  const float* tf2w  = (const float*)d_in[24];
  const float* tf2b  = (const float*)d_in[25];
  const float* f0w   = (const float*)d_in[26];
  const float* f0b   = (const float*)d_in[27];
  const float* f0g   = (const float*)d_in[28];
  const float* f0bb  = (const float*)d_in[29];
  const float* f1w   = (const float*)d_in[30];
  const float* f1b   = (const float*)d_in[31];
  const float* f1g   = (const float*)d_in[32];
  const float* f1bb  = (const float*)d_in[33];
  const float* fow   = (const float*)d_in[34];
  const float* fob   = (const float*)d_in[35];
  float* out = (float*)d_out;

  char* ws = (char*)d_ws;
  size_t off = 0;
  float* H1  = (float*)(ws + off);  off += (size_t)cL2 * cH * 4;
  float* H0  = (float*)(ws + off);  off += (size_t)cL2 * cH * 4;
  float* XW  = (float*)(ws + off);  off += (size_t)cL2 * cH * 4;
  float* DEG = (float*)(ws + off);  off += (size_t)cL2 * 4;
  int*   L2B = (int*)(ws + off);    off += (size_t)cL2 * 4;
  int*   CNT = (int*)(ws + off);    off += (size_t)cL2 * 4;
  char*  ST  = ws + off;            off += 3 * ((size_t)cG * cH * 4 * 3 + cG * 4);
  int*   CSR1 = (int*)(ws + off);   off += (size_t)cN * CAP1 * 4;
  int*   CSR2 = (int*)(ws + off);   off += (size_t)cL2 * CAP2 * 4;
  // split-bf16 weight buffers
  unsigned short* WinH  = (unsigned short*)(ws + off); off += (size_t)cNL * 384 * 128 * 2;
  unsigned short* WinL  = (unsigned short*)(ws + off); off += (size_t)cNL * 384 * 128 * 2;
  unsigned short* WoutH = (unsigned short*)(ws + off); off += (size_t)cNL * 128 * 128 * 2;
  unsigned short* WoutL = (unsigned short*)(ws + off); off += (size_t)cNL * 128 * 128 * 2;
  unsigned short* Wf1H  = (unsigned short*)(ws + off); off += (size_t)cNL * 256 * 128 * 2;
  unsigned short* Wf1L  = (unsigned short*)(ws + off); off += (size_t)cNL * 256 * 128 * 2;
  unsigned short* Wf2H  = (unsigned short*)(ws + off); off += (size_t)cNL * 128 * 256 * 2;
  unsigned short* Wf2L  = (unsigned short*)(ws + off); off += (size_t)cNL * 128 * 256 * 2;

  size_t st_stride = (size_t)cG * cH * 4 * 3 + cG * 4;
  auto stat = [&](int p) {
    char* b = ST + p * st_stride;
    struct S { float* sum; unsigned* mx; unsigned* mn; float* cnt; } s;
    s.sum = (float*)b;
    s.mx  = (unsigned*)(b + (size_t)cG * cH * 4);
    s.mn  = (unsigned*)(b + (size_t)cG * cH * 8);
    s.cnt = (float*)(b + (size_t)cG * cH * 12);
    return s;
  };
  auto s0 = stat(0), s1 = stat(1), s2 = stat(2);

  // 0) split transformer weights into bf16 hi/lo; init all pool stats
  split_w_k<<<(cNL * 384 * 128 + 255) / 256, 256, 0, stream>>>(tinw, WinH, WinL, cNL * 384 * 128);
  split_w_k<<<(cNL * 128 * 128 + 255) / 256, 256, 0, stream>>>(toutw, WoutH, WoutL, cNL * 128 * 128);
  split_w_k<<<(cNL * 256 * 128 + 255) / 256, 256, 0, stream>>>(tf1w, Wf1H, Wf1L, cNL * 256 * 128);
  split_w_k<<<(cNL * 128 * 256 + 255) / 256, 256, 0, stream>>>(tf2w, Wf2H, Wf2L, cNL * 128 * 256);
  init_stats3_k<<<(cG * cH + 255) / 256, 256, 0, stream>>>(ST, st_stride);

  // 1) GCN1 -> H0 (CSR gather; dinv derived from CSR counts)
  gemm128_k<<<(cN + 127) / 128, 256, 0, stream>>>(x, g1w, XW, cN);
  fill_k<<<(cN + 255) / 256, 256, 0, stream>>>((float*)CNT, 0.0f, cN);   // int 0
  csr_fill_k<<<(cE + 255) / 256, 256, 0, stream>>>(ei, CNT, CSR1, CAP1, cE);
  cnt_to_dinv_k<<<(cN + 255) / 256, 256, 0, stream>>>(CNT, DEG, cN);
  gcn_gather_k<1><<<(cN + 3) / 4, 256, 0, stream>>>(XW, DEG, CSR1, CNT, g1b, H0,
      nullptr, nullptr, nullptr, nullptr, nullptr, cN, CAP1);

  // 2) fused MFMA transformer encoder -> H1 (+pool H1, +L2B); 1024-thr blocks
  hipFuncSetAttribute(reinterpret_cast<const void*>(encoder_k),
                      hipFuncAttributeMaxDynamicSharedMemorySize, 131072);
  encoder_k<<<cL2 / ESETS, 1024, SMEM_SZ, stream>>>(H0, ea, lew, leb, ue, l2nm, batch,
      WinH, WinL, tinb, WoutH, WoutL, toutb, tl1g, tl1b, tl2g, tl2b,
      Wf1H, Wf1L, tf1b, Wf2H, Wf2L, tf2b, H1,
      s1.sum, s1.mx, s1.mn, s1.cnt, L2B);

  // 3) pool H0 (sorted batch -> segmented)
  pool_sorted_k<<<(int)((((long)(cN + 7) / 8) * 32 + 255) / 256), 256, 0, stream>>>(
      H0, batch, s0.sum, s0.mx, s0.mn, s0.cnt, cN);

  // 4) GCN2 (CSR gather, relu+pool fused; H2 never materialized)
  gemm128_k<<<(cL2 + 127) / 128, 256, 0, stream>>>(H1, g2w, XW, cL2);
  fill_k<<<(cL2 + 255) / 256, 256, 0, stream>>>((float*)CNT, 0.0f, cL2);
  csr_fill_k<<<(cEL + 255) / 256, 256, 0, stream>>>(l2ei, CNT, CSR2, CAP2, cEL);
  cnt_to_dinv_k<<<(cL2 + 255) / 256, 256, 0, stream>>>(CNT, DEG, cL2);
  gcn_gather_k<0><<<(cL2 + 3) / 4, 256, 0, stream>>>(XW, DEG, CSR2, CNT, g2b, nullptr,
      L2B, s2.sum, s2.mx, s2.mn, s2.cnt, cL2, CAP2);

  // 5) final MLP -> out[512] (pool finalize fused into prologue)
  mlp_k<<<cG, 128, 0, stream>>>(ST, st_stride, f0w, f0b, f0g, f0bb, f1w, f1b, f1g, f1bb, fow, fob, out);
}

// Round 11
// 4254.808 us; speedup vs baseline: 1.5987x; 1.5987x over previous
//
#include <hip/hip_runtime.h>

// ---------------- problem constants ----------------
constexpr int cN  = 50000;
constexpr int cE  = 800000;
constexpr int cEU = 400000;
constexpr int cL2 = 131072;
constexpr int cEL = 1048576;
constexpr int cG  = 512;
constexpr int cH  = 128;
constexpr int cNH = 4;
constexpr int cNL = 2;

// CSR capacities. deg ~ Poisson(16) for GCN1, Poisson(8) for GCN2.
constexpr int CAP1 = 64;
constexpr int CAP2 = 48;

// encoder geometry — ESETS=8 (48 rows = 3 full M-tiles, ZERO pad waste),
// 512 threads, __launch_bounds__(512,1). VERIFIED OPTIMUM (R7: 3662 us).
// Occupancy notes (R8-R10): 16 waves/CU requires total VGPR<=128 which this
// kernel cannot meet without spilling (4-8 GB scratch, net loss). 8 waves +
// zero pad + no spill beats every higher-occupancy variant tried.
constexpr int ESETS = 8;          // sets per encoder block
constexpr int ERT   = ESETS * 6;  // 48 token rows = 3 M-tiles of 16
constexpr int MT    = 3;
constexpr int QS    = 388;        // fp32 QKV LDS stride (388 % 32 == 4)
constexpr int AS    = 264;        // bf16 A LDS stride

// dynamic LDS layout (bytes)
constexpr int OFF_QKV = 0;                        // 48*388*4 = 74496
constexpr int OFF_AH  = 74496;                    // 48*264*2 = 25344
constexpr int OFF_AL  = OFF_AH + 25344;           // 99840
constexpr int OFF_ATT = OFF_AL + 25344;           // 125184 ; 8*144*4 = 4608
constexpr int OFF_IDX = OFF_ATT + 4608;           // 129792 ; 48 ints = 192
constexpr int SMEM_SZ = OFF_IDX + 192;            // 129,984 B (1 block/CU)

typedef __attribute__((ext_vector_type(8))) short short8v;
typedef __attribute__((ext_vector_type(4))) float f32x4;

#define DEVI __device__ __forceinline__

DEVI unsigned fmap(float x) {
  unsigned u = __float_as_uint(x);
  return (u & 0x80000000u) ? ~u : (u | 0x80000000u);
}
DEVI float funmap(unsigned m) {
  return __uint_as_float((m & 0x80000000u) ? (m & 0x7FFFFFFFu) : ~m);
}
DEVI float gelu_exact(float x) {
  return 0.5f * x * (1.0f + erff(x * 0.70710678118654752f));
}
DEVI unsigned short f2b_rn(float x) {            // fp32 -> bf16 round-nearest-even
  unsigned u = __float_as_uint(x);
  return (unsigned short)((u + 0x7FFFu + ((u >> 16) & 1u)) >> 16);
}
DEVI float b2f(unsigned short h) { return __uint_as_float(((unsigned)h) << 16); }
// packed split writes: 2 consecutive cols -> one b32 per array (idx must be even)
DEVI void sp2(unsigned short* hi, unsigned short* lo, int idx, float a0, float a1) {
  unsigned short h0 = f2b_rn(a0), h1 = f2b_rn(a1);
  unsigned short l0 = f2b_rn(a0 - b2f(h0)), l1 = f2b_rn(a1 - b2f(h1));
  *(unsigned*)&hi[idx] = (unsigned)h0 | ((unsigned)h1 << 16);
  *(unsigned*)&lo[idx] = (unsigned)l0 | ((unsigned)l1 << 16);
}
// 4 consecutive cols -> one b64 per array (idx must be multiple of 4)
DEVI void sp4(unsigned short* hi, unsigned short* lo, int idx, float4 v) {
  unsigned short h0 = f2b_rn(v.x), h1 = f2b_rn(v.y), h2 = f2b_rn(v.z), h3 = f2b_rn(v.w);
  unsigned short l0 = f2b_rn(v.x - b2f(h0)), l1 = f2b_rn(v.y - b2f(h1));
  unsigned short l2 = f2b_rn(v.z - b2f(h2)), l3 = f2b_rn(v.w - b2f(h3));
  uint2 H, L;
  H.x = (unsigned)h0 | ((unsigned)h1 << 16);
  H.y = (unsigned)h2 | ((unsigned)h3 << 16);
  L.x = (unsigned)l0 | ((unsigned)l1 << 16);
  L.y = (unsigned)l2 | ((unsigned)l3 << 16);
  *(uint2*)&hi[idx] = H;
  *(uint2*)&lo[idx] = L;
}

// ---------------- tiny utility kernels ----------------
__global__ void fill_k(float* p, float v, int n) {
  int i = blockIdx.x * 256 + threadIdx.x;
  if (i < n) p[i] = v;
}

// dinv from CSR counts: degree = cnt (edges) + 1 (self loop)
__global__ void cnt_to_dinv_k(const int* __restrict__ cnt, float* __restrict__ dinv, int n) {
  int i = blockIdx.x * 256 + threadIdx.x;
  if (i < n) dinv[i] = rsqrtf((float)cnt[i] + 1.0f);
}

// bucket edges by destination into fixed-capacity CSR (1 int atomic / edge)
__global__ void csr_fill_k(const int* __restrict__ ei, int* __restrict__ cnt,
                           int* __restrict__ csr, int cap, int nE) {
  int e = blockIdx.x * 256 + threadIdx.x;
  if (e >= nE) return;
  int s = ei[e], d = ei[nE + e];
  int slot = atomicAdd(&cnt[d], 1);
  if (slot < cap) csr[(long)d * cap + slot] = s;
}

// split fp32 weights into bf16 hi/lo (error-compensated MFMA operands)
__global__ void split_w_k(const float* __restrict__ src, unsigned short* __restrict__ hi,
                          unsigned short* __restrict__ lo, int n) {
  int i = blockIdx.x * 256 + threadIdx.x;
  if (i < n) {
    float x = src[i];
    unsigned short h = f2b_rn(x);
    hi[i] = h;
    lo[i] = f2b_rn(x - b2f(h));
  }
}

// ---------------- generic C[M,128] = A[M,128] @ W[128,128]^T ----------------
__global__ __launch_bounds__(256) void gemm128_k(const float* __restrict__ A,
                                                 const float* __restrict__ W,
                                                 float* __restrict__ C, int M) {
  __shared__ float At[16][132];
  int c = threadIdx.x & 127, rr = threadIdx.x >> 7;
  int base = blockIdx.x * 128;
  for (int tile = 0; tile < 8; ++tile) {
    int r0 = base + tile * 16;
    if (r0 >= M) break;
    __syncthreads();
    for (int i = threadIdx.x; i < 16 * 32; i += 256) {
      int r = i >> 5, s4 = (i & 31) * 4;
      if (r0 + r < M) *(float4*)&At[r][s4] = *(const float4*)&A[(long)(r0 + r) * cH + s4];
    }
    __syncthreads();
    float acc[8];
    #pragma unroll
    for (int j = 0; j < 8; ++j) acc[j] = 0.f;
    const float* wr = W + (long)c * cH;
    for (int k = 0; k < cH; k += 4) {
      float4 w4 = *(const float4*)(wr + k);
      #pragma unroll
      for (int j = 0; j < 8; ++j) {
        float4 a4 = *(const float4*)&At[rr * 8 + j][k];
        acc[j] = fmaf(a4.x, w4.x, acc[j]);
        acc[j] = fmaf(a4.y, w4.y, acc[j]);
        acc[j] = fmaf(a4.z, w4.z, acc[j]);
        acc[j] = fmaf(a4.w, w4.w, acc[j]);
      }
    }
    #pragma unroll
    for (int j = 0; j < 8; ++j) {
      int r = r0 + rr * 8 + j;
      if (r < M) C[(long)r * cH + c] = acc[j];
    }
  }
}

// ---------------- GCN aggregation, gather form (NO column atomics) ----------------
// one wave per row; lane covers 2 cols. self-loop folded in (dinv^2 * xw + bias).
// STORE=1: write out row (GCN1 -> H0). STORE=0: relu + pool atomics (GCN2),
// H2 never materialized.
template<int STORE>
__global__ __launch_bounds__(256) void gcn_gather_k(
    const float* __restrict__ xw, const float* __restrict__ dinv,
    const int* __restrict__ csr, const int* __restrict__ cnt,
    const float* __restrict__ bias, float* __restrict__ out,
    const int* __restrict__ gidx,
    float* __restrict__ sum, unsigned* __restrict__ mx, unsigned* __restrict__ mn,
    float* __restrict__ ccnt, int n, int cap) {
  int wv = threadIdx.x >> 6, lane = threadIdx.x & 63;
  int r = blockIdx.x * 4 + wv;
  if (r >= n) return;
  int c = lane * 2;
  float di = dinv[r];
  float2 v0 = *(const float2*)&xw[(long)r * cH + c];
  float2 b2 = *(const float2*)&bias[c];
  float a0 = b2.x + di * di * v0.x;
  float a1 = b2.y + di * di * v0.y;
  int deg = cnt[r];
  if (deg > cap) deg = cap;
  long base = (long)r * cap;
  for (int k = 0; k < deg; ++k) {
    int s = csr[base + k];                      // wave-uniform -> scalar load
    float w = dinv[s] * di;
    float2 v = *(const float2*)&xw[(long)s * cH + c];
    a0 = fmaf(w, v.x, a0);
    a1 = fmaf(w, v.y, a1);
  }
  if (STORE) {
    float2 o; o.x = a0; o.y = a1;
    *(float2*)&out[(long)r * cH + c] = o;
  } else {
    a0 = fmaxf(a0, 0.f);
    a1 = fmaxf(a1, 0.f);
    int g = gidx[r];
    long b = (long)g * cH + c;
    atomicAdd(&sum[b + 0], a0); atomicAdd(&sum[b + 1], a1);
    atomicMax(&mx[b + 0], fmap(a0)); atomicMax(&mx[b + 1], fmap(a1));
    atomicMin(&mn[b + 0], fmap(a0)); atomicMin(&mn[b + 1], fmap(a1));
    if (lane == 0) atomicAdd(&ccnt[g], 1.0f);
  }
}

// ---------------- fused 2-layer transformer encoder (MFMA split-bf16) ----------------
// 8 sets x 6 tokens = 48 rows = 3 M-tiles. 512 threads / 8 waves.
// ks-outer / m-inner with THREE independent accumulators per m (accH/accL1/
// accL2) = 9 independent MFMA chains. ff1 raw acc staged in free QKV LDS
// columns (no dreg registers -> no spill). Fused per-wave attention.
// Epilogue fuses H1 mean + H1 pooling atomics + L2B computation.
__global__ __launch_bounds__(512, 1) void encoder_k(
    const float* __restrict__ H0, const float* __restrict__ EA,
    const float* __restrict__ LEW, const float* __restrict__ LEB,
    const int* __restrict__ ue, const int* __restrict__ l2nm,
    const int* __restrict__ batch,
    const unsigned short* __restrict__ WinH, const unsigned short* __restrict__ WinL,
    const float* __restrict__ Bin,
    const unsigned short* __restrict__ WoutH, const unsigned short* __restrict__ WoutL,
    const float* __restrict__ Bout,
    const float* __restrict__ Ln1g, const float* __restrict__ Ln1b,
    const float* __restrict__ Ln2g, const float* __restrict__ Ln2b,
    const unsigned short* __restrict__ Wf1H, const unsigned short* __restrict__ Wf1L,
    const float* __restrict__ Bf1,
    const unsigned short* __restrict__ Wf2H, const unsigned short* __restrict__ Wf2L,
    const float* __restrict__ Bf2,
    float* __restrict__ H1,
    float* __restrict__ sum1, unsigned* __restrict__ mx1, unsigned* __restrict__ mn1,
    float* __restrict__ cnt1, int* __restrict__ l2b) {
  extern __shared__ char smem[];
  float* QKV = (float*)(smem + OFF_QKV);               // [48][388] fp32
  unsigned short* Ahs = (unsigned short*)(smem + OFF_AH); // [48][264] bf16 hi
  unsigned short* Als = (unsigned short*)(smem + OFF_AL); // [48][264] bf16 lo
  float* att = (float*)(smem + OFF_ATT);               // [8][144]
  int* nidx = (int*)(smem + OFF_IDX);                  // 32 node ids
  int* eidx = nidx + 32;                               // 16 edge ids

  const int tid = threadIdx.x;
  const int lane = tid & 63, wv = tid >> 6;
  const int lr = lane & 15, lq = lane >> 4;
  const int base = blockIdx.x * ESETS;

  if (tid < ESETS) {
    int e = l2nm[base + tid];
    int f = l2nm[cL2 + base + tid];
    eidx[tid * 2 + 0] = e;
    eidx[tid * 2 + 1] = f;
    nidx[tid * 4 + 0] = ue[e];
    nidx[tid * 4 + 1] = ue[cEU + e];
    nidx[tid * 4 + 2] = ue[f];
    nidx[tid * 4 + 3] = ue[cEU + f];
  }
  __syncthreads();
  // H0 rows (4 per set) -> A hi/lo (packed b64 writes)
  for (int i = tid; i < 32 * 32; i += 512) {
    int q = i >> 5, s4 = (i & 31) * 4;
    int r = (q >> 2) * 6 + (q & 3);
    float4 v = *(const float4*)&H0[(long)nidx[q] * cH + s4];
    sp4(Ahs, Als, r * AS + s4, v);
  }
  // edge rows (2 per set): EA[e] @ LEW^T + LEB; 2 cols/thread, packed write
  for (int i = tid; i < ESETS * cH; i += 512) {     // 1024 items
    int c = (i & 63) * 2, q = i >> 6;
    const float* row = EA + (long)eidx[q] * 16;
    const float* w0 = LEW + c * 16;
    const float* w1 = LEW + (c + 1) * 16;
    float2 bb2 = *(const float2*)&LEB[c];
    float a0 = bb2.x, a1 = bb2.y;
    #pragma unroll
    for (int d = 0; d < 16; ++d) {
      float rv = row[d];
      a0 = fmaf(rv, w0[d], a0);
      a1 = fmaf(rv, w1[d], a1);
    }
    int r = (q >> 1) * 6 + 4 + (q & 1);
    sp2(Ahs, Als, r * AS + c, a0, a1);
  }
  __syncthreads();

  for (int l = 0; l < cNL; ++l) {
    // ---- qkv: [48,128] @ Win^T -> QKV fp32 [48][0..384) ----
    {
      const unsigned short* WH = WinH + (long)l * 384 * 128;
      const unsigned short* WL = WinL + (long)l * 384 * 128;
      const float* BB = Bin + l * 384;
      #pragma unroll
      for (int ni = 0; ni < 3; ++ni) {
        int col = (wv + 8 * ni) * 16 + lr;
        const unsigned short* wp = WH + (long)col * 128 + (lq << 3);
        const unsigned short* wq = WL + (long)col * 128 + (lq << 3);
        f32x4 accH[MT], accL1[MT], accL2[MT];
        #pragma unroll
        for (int m = 0; m < MT; ++m) {
          accH[m] = (f32x4){0.f, 0.f, 0.f, 0.f};
          accL1[m] = (f32x4){0.f, 0.f, 0.f, 0.f};
          accL2[m] = (f32x4){0.f, 0.f, 0.f, 0.f};
        }
        #pragma unroll
        for (int ks = 0; ks < 4; ++ks) {
          short8v bh = *(const short8v*)&wp[ks * 32];
          short8v bl = *(const short8v*)&wq[ks * 32];
          #pragma unroll
          for (int m = 0; m < MT; ++m) {
            int ao = (m * 16 + lr) * AS + (lq << 3) + ks * 32;
            short8v ah = *(const short8v*)&Ahs[ao];
            short8v al = *(const short8v*)&Als[ao];
            accL1[m] = __builtin_amdgcn_mfma_f32_16x16x32_bf16(al, bh, accL1[m], 0, 0, 0);
            accL2[m] = __builtin_amdgcn_mfma_f32_16x16x32_bf16(ah, bl, accL2[m], 0, 0, 0);
            accH[m] = __builtin_amdgcn_mfma_f32_16x16x32_bf16(ah, bh, accH[m], 0, 0, 0);
          }
        }
        float bv = BB[col];
        #pragma unroll
        for (int m = 0; m < MT; ++m) {
          int r0 = m * 16 + (lq << 2);
          #pragma unroll
          for (int j = 0; j < 4; ++j)
            QKV[(r0 + j) * QS + col] = accH[m][j] + (accL1[m][j] + accL2[m][j]) + bv;
        }
      }
    }
    __syncthreads();
    // ---- fused attention: wave s owns set s; no block barriers inside ----
    {
      const int s = wv;
      float* attS = att + s * 144;
      if (lane < 24) {
        int h = lane / 6, qt = lane % 6;
        const float* qp = &QKV[(s * 6 + qt) * QS + h * 32];
        float4 qv[8];
        #pragma unroll
        for (int j4 = 0; j4 < 8; ++j4) qv[j4] = *(const float4*)&qp[j4 * 4];
        float sc[6];
        #pragma unroll
        for (int kt = 0; kt < 6; ++kt) {
          const float* kp = &QKV[(s * 6 + kt) * QS + 128 + h * 32];
          float d = 0.f;
          #pragma unroll
          for (int j4 = 0; j4 < 8; ++j4) {
            float4 b4 = *(const float4*)&kp[j4 * 4];
            d = fmaf(qv[j4].x, b4.x, d); d = fmaf(qv[j4].y, b4.y, d);
            d = fmaf(qv[j4].z, b4.z, d); d = fmaf(qv[j4].w, b4.w, d);
          }
          sc[kt] = d * 0.17677669529663687f;   // 1/sqrt(32)
        }
        float mx = sc[0];
        #pragma unroll
        for (int kt = 1; kt < 6; ++kt) mx = fmaxf(mx, sc[kt]);
        float ev[6]; float sum = 0.f;
        #pragma unroll
        for (int kt = 0; kt < 6; ++kt) { ev[kt] = expf(sc[kt] - mx); sum += ev[kt]; }
        float inv = 1.f / sum;
        #pragma unroll
        for (int kt = 0; kt < 6; ++kt) attS[(h * 6 + qt) * 6 + kt] = ev[kt] * inv;
      }
      // wave-local fence: prob writes -> AV reads (same wave, no block barrier)
      asm volatile("s_waitcnt lgkmcnt(0)" ::: "memory");
      __builtin_amdgcn_sched_barrier(0);
      // AV: 2 cols per lane, float2 V reads, packed b32 writes
      {
        int c = lane * 2;
        int h = c >> 5;
        #pragma unroll
        for (int r = 0; r < 6; ++r) {
          const float* arow = &attS[(h * 6 + r) * 6];
          float d0 = 0.f, d1 = 0.f;
          #pragma unroll
          for (int kt = 0; kt < 6; ++kt) {
            float2 v2 = *(const float2*)&QKV[(s * 6 + kt) * QS + 256 + c];
            float a = arow[kt];
            d0 = fmaf(a, v2.x, d0);
            d1 = fmaf(a, v2.y, d1);
          }
          sp2(Ahs, Als, (s * 6 + r) * AS + 128 + c, d0, d1);
        }
      }
    }
    __syncthreads();
    // ---- out-proj: A[.][128..256) @ Wout^T -> QKV fp32 [.][0..128) ----
    {
      const unsigned short* WH = WoutH + (long)l * 128 * 128;
      const unsigned short* WL = WoutL + (long)l * 128 * 128;
      int col = wv * 16 + lr;
      const unsigned short* wp = WH + (long)col * 128 + (lq << 3);
      const unsigned short* wq = WL + (long)col * 128 + (lq << 3);
      f32x4 accH[MT], accL1[MT], accL2[MT];
      #pragma unroll
      for (int m = 0; m < MT; ++m) {
        accH[m] = (f32x4){0.f, 0.f, 0.f, 0.f};
        accL1[m] = (f32x4){0.f, 0.f, 0.f, 0.f};
        accL2[m] = (f32x4){0.f, 0.f, 0.f, 0.f};
      }
      #pragma unroll
      for (int ks = 0; ks < 4; ++ks) {
        short8v bh = *(const short8v*)&wp[ks * 32];
        short8v bl = *(const short8v*)&wq[ks * 32];
        #pragma unroll
        for (int m = 0; m < MT; ++m) {
          int ao = (m * 16 + lr) * AS + 128 + (lq << 3) + ks * 32;
          short8v ah = *(const short8v*)&Ahs[ao];
          short8v al = *(const short8v*)&Als[ao];
          accL1[m] = __builtin_amdgcn_mfma_f32_16x16x32_bf16(al, bh, accL1[m], 0, 0, 0);
          accL2[m] = __builtin_amdgcn_mfma_f32_16x16x32_bf16(ah, bl, accL2[m], 0, 0, 0);
          accH[m] = __builtin_amdgcn_mfma_f32_16x16x32_bf16(ah, bh, accH[m], 0, 0, 0);
        }
      }
      float bv = Bout[l * 128 + col];
      #pragma unroll
      for (int m = 0; m < MT; ++m) {
        int r0 = m * 16 + (lq << 2);
        #pragma unroll
        for (int j = 0; j < 4; ++j)
          QKV[(r0 + j) * QS + col] = accH[m][j] + (accL1[m][j] + accL2[m][j]) + bv;
      }
    }
    __syncthreads();
    // ---- residual + LN1 (packed): y = xs + attn -> A[0..128) and QKV[128..256) ----
    {
      const float* gg = Ln1g + l * cH;
      const float* bb = Ln1b + l * cH;
      #pragma unroll
      for (int p = 0; p < MT; ++p) {
        int r = p * 16 + (tid >> 5);
        int c0 = (tid & 31) * 4;
        ushort4 ah4 = *(const ushort4*)&Ahs[r * AS + c0];
        ushort4 al4 = *(const ushort4*)&Als[r * AS + c0];
        float4 q4 = *(const float4*)&QKV[r * QS + c0];
        float y[4];
        y[0] = b2f(ah4.x) + b2f(al4.x) + q4.x;
        y[1] = b2f(ah4.y) + b2f(al4.y) + q4.y;
        y[2] = b2f(ah4.z) + b2f(al4.z) + q4.z;
        y[3] = b2f(ah4.w) + b2f(al4.w) + q4.w;
        float s = 0.f, s2 = 0.f;
        #pragma unroll
        for (int j = 0; j < 4; ++j) { s += y[j]; s2 += y[j] * y[j]; }
        #pragma unroll
        for (int m = 1; m < 32; m <<= 1) { s += __shfl_xor(s, m, 32); s2 += __shfl_xor(s2, m, 32); }
        float mean = s * (1.f / 128.f);
        float rstd = rsqrtf(s2 * (1.f / 128.f) - mean * mean + 1e-5f);
        float4 g4 = *(const float4*)&gg[c0];
        float4 b4v = *(const float4*)&bb[c0];
        float4 xn4;
        xn4.x = (y[0] - mean) * rstd * g4.x + b4v.x;
        xn4.y = (y[1] - mean) * rstd * g4.y + b4v.y;
        xn4.z = (y[2] - mean) * rstd * g4.z + b4v.z;
        xn4.w = (y[3] - mean) * rstd * g4.w + b4v.w;
        *(float4*)&QKV[r * QS + 128 + c0] = xn4;   // residual master for LN2
        sp4(Ahs, Als, r * AS + c0, xn4);           // A operand for ff1
      }
    }
    __syncthreads();
    // ---- ff1: A[0..128) @ Wf1^T (N=256) -> raw acc into FREE QKV cols ----
    // free fp32 LDS cols: [0..128) (attn-out, dead) and [256..384) (V, dead);
    // [128..256) is the LIVE LN1 residual master -> avoided by the lc mapping.
    {
      const unsigned short* WH = Wf1H + (long)l * 256 * 128;
      const unsigned short* WL = Wf1L + (long)l * 256 * 128;
      #pragma unroll
      for (int ni = 0; ni < 2; ++ni) {
        int col = (wv + 8 * ni) * 16 + lr;
        const unsigned short* wp = WH + (long)col * 128 + (lq << 3);
        const unsigned short* wq = WL + (long)col * 128 + (lq << 3);
        f32x4 accH[MT], accL1[MT], accL2[MT];
        #pragma unroll
        for (int m = 0; m < MT; ++m) {
          accH[m] = (f32x4){0.f, 0.f, 0.f, 0.f};
          accL1[m] = (f32x4){0.f, 0.f, 0.f, 0.f};
          accL2[m] = (f32x4){0.f, 0.f, 0.f, 0.f};
        }
        #pragma unroll
        for (int ks = 0; ks < 4; ++ks) {
          short8v bh = *(const short8v*)&wp[ks * 32];
          short8v bl = *(const short8v*)&wq[ks * 32];
          #pragma unroll
          for (int m = 0; m < MT; ++m) {
            int ao = (m * 16 + lr) * AS + (lq << 3) + ks * 32;
            short8v ah = *(const short8v*)&Ahs[ao];
            short8v al = *(const short8v*)&Als[ao];
            accL1[m] = __builtin_amdgcn_mfma_f32_16x16x32_bf16(al, bh, accL1[m], 0, 0, 0);
            accL2[m] = __builtin_amdgcn_mfma_f32_16x16x32_bf16(ah, bl, accL2[m], 0, 0, 0);
            accH[m] = __builtin_amdgcn_mfma_f32_16x16x32_bf16(ah, bh, accH[m], 0, 0, 0);
          }
        }
        int lc = col + (col >= 128 ? 128 : 0);   // map into free cols
        #pragma unroll
        for (int m = 0; m < MT; ++m) {
          int r0 = m * 16 + (lq << 2);
          #pragma unroll
          for (int j = 0; j < 4; ++j)
            QKV[(r0 + j) * QS + lc] = accH[m][j] + (accL1[m][j] + accL2[m][j]);
        }
      }
    }
    __syncthreads();   // ff1 acc written; A reads done
    // ---- relu + bias + split (packed): QKV free cols -> A hi/lo [0..256) ----
    for (int i = tid; i < ERT * 128; i += 512) {
      int r = i >> 7, n = (i & 127) * 2;
      int lc = n + (n >= 128 ? 128 : 0);
      float2 v2 = *(const float2*)&QKV[r * QS + lc];
      float2 bb2 = *(const float2*)&Bf1[l * 256 + n];
      float h0 = fmaxf(v2.x + bb2.x, 0.f);
      float h1 = fmaxf(v2.y + bb2.y, 0.f);
      sp2(Ahs, Als, r * AS + n, h0, h1);
    }
    __syncthreads();
    // ---- ff2: A[0..256) @ Wf2^T (K=256) -> QKV fp32 [0..128) ----
    {
      const unsigned short* WH = Wf2H + (long)l * 128 * 256;
      const unsigned short* WL = Wf2L + (long)l * 128 * 256;
      int col = wv * 16 + lr;
      const unsigned short* wp = WH + (long)col * 256 + (lq << 3);
      const unsigned short* wq = WL + (long)col * 256 + (lq << 3);
      f32x4 accH[MT], accL1[MT], accL2[MT];
      #pragma unroll
      for (int m = 0; m < MT; ++m) {
        accH[m] = (f32x4){0.f, 0.f, 0.f, 0.f};
        accL1[m] = (f32x4){0.f, 0.f, 0.f, 0.f};
        accL2[m] = (f32x4){0.f, 0.f, 0.f, 0.f};
      }
      #pragma unroll
      for (int ks = 0; ks < 8; ++ks) {
        short8v bh = *(const short8v*)&wp[ks * 32];
        short8v bl = *(const short8v*)&wq[ks * 32];
        #pragma unroll
        for (int m = 0; m < MT; ++m) {
          int ao = (m * 16 + lr) * AS + (lq << 3) + ks * 32;
          short8v ah = *(const short8v*)&Ahs[ao];
          short8v al = *(const short8v*)&Als[ao];
          accL1[m] = __builtin_amdgcn_mfma_f32_16x16x32_bf16(al, bh, accL1[m], 0, 0, 0);
          accL2[m] = __builtin_amdgcn_mfma_f32_16x16x32_bf16(ah, bl, accL2[m], 0, 0, 0);
          accH[m] = __builtin_amdgcn_mfma_f32_16x16x32_bf16(ah, bh, accH[m], 0, 0, 0);
        }
      }
      float bv = Bf2[l * 128 + col];
      #pragma unroll
      for (int m = 0; m < MT; ++m) {
        int r0 = m * 16 + (lq << 2);
        #pragma unroll
        for (int j = 0; j < 4; ++j)
          QKV[(r0 + j) * QS + col] = accH[m][j] + (accL1[m][j] + accL2[m][j]) + bv;
      }
    }
    __syncthreads();
    // ---- residual + LN2 (packed): QKV[128..256) + QKV[0..128) -> A hi/lo ----
    {
      const float* gg = Ln2g + l * cH;
      const float* bb = Ln2b + l * cH;
      #pragma unroll
      for (int p = 0; p < MT; ++p) {
        int r = p * 16 + (tid >> 5);
        int c0 = (tid & 31) * 4;
        float4 qa = *(const float4*)&QKV[r * QS + 128 + c0];
        float4 qb = *(const float4*)&QKV[r * QS + c0];
        float y[4];
        y[0] = qa.x + qb.x; y[1] = qa.y + qb.y;
        y[2] = qa.z + qb.z; y[3] = qa.w + qb.w;
        float s = 0.f, s2 = 0.f;
        #pragma unroll
        for (int j = 0; j < 4; ++j) { s += y[j]; s2 += y[j] * y[j]; }
        #pragma unroll
        for (int m = 1; m < 32; m <<= 1) { s += __shfl_xor(s, m, 32); s2 += __shfl_xor(s2, m, 32); }
        float mean = s * (1.f / 128.f);
        float rstd = rsqrtf(s2 * (1.f / 128.f) - mean * mean + 1e-5f);
        float4 g4 = *(const float4*)&gg[c0];
        float4 b4v = *(const float4*)&bb[c0];
        float4 xn4;
        xn4.x = (y[0] - mean) * rstd * g4.x + b4v.x;
        xn4.y = (y[1] - mean) * rstd * g4.y + b4v.y;
        xn4.z = (y[2] - mean) * rstd * g4.z + b4v.z;
        xn4.w = (y[3] - mean) * rstd * g4.w + b4v.w;
        sp4(Ahs, Als, r * AS + c0, xn4);
      }
    }
    __syncthreads();
  }

  // ---- epilogue: H1 = mean over 6 tokens; fused H1 pooling + L2B (packed) ----
  {
    int s = tid >> 6, c = (tid & 63) * 2;      // 512 threads = 8 sets x 64 pairs
    float m0 = 0.f, m1 = 0.f;
    #pragma unroll
    for (int t = 0; t < 6; ++t) {
      unsigned hh = *(const unsigned*)&Ahs[(s * 6 + t) * AS + c];
      unsigned ll = *(const unsigned*)&Als[(s * 6 + t) * AS + c];
      m0 += b2f((unsigned short)(hh & 0xFFFFu)) + b2f((unsigned short)(ll & 0xFFFFu));
      m1 += b2f((unsigned short)(hh >> 16)) + b2f((unsigned short)(ll >> 16));
    }
    float v0 = m0 * (1.f / 6.f), v1 = m1 * (1.f / 6.f);
    float2 o; o.x = v0; o.y = v1;
    *(float2*)&H1[(long)(base + s) * cH + c] = o;
    int g = batch[nidx[s * 4]];               // l2_batch = batch[ue0[l2nm0]]
    long b = (long)g * cH + c;
    atomicAdd(&sum1[b + 0], v0);  atomicAdd(&sum1[b + 1], v1);
    atomicMax(&mx1[b + 0], fmap(v0)); atomicMax(&mx1[b + 1], fmap(v1));
    atomicMin(&mn1[b + 0], fmap(v0)); atomicMin(&mn1[b + 1], fmap(v1));
    if (c == 0) {
      atomicAdd(&cnt1[g], 1.0f);
      l2b[base + s] = g;
    }
  }
}

// ---------------- pooling ----------------
// init all 3 stat sets in one dispatch
__global__ void init_stats3_k(char* ST, size_t stride) {
  int i = blockIdx.x * 256 + threadIdx.x;
  if (i >= cG * cH) return;
  #pragma unroll
  for (int p = 0; p < 3; ++p) {
    char* b = ST + (size_t)p * stride;
    ((float*)b)[i] = 0.f;
    ((unsigned*)(b + (size_t)cG * cH * 4))[i] = 0u;
    ((unsigned*)(b + (size_t)cG * cH * 8))[i] = 0xFFFFFFFFu;
    if (i < cG) ((float*)(b + (size_t)cG * cH * 12))[i] = 0.f;
  }
}

// segmented pool over SORTED group index (batch): ~8x fewer atomics
__global__ void pool_sorted_k(const float* __restrict__ X, const int* __restrict__ gidx,
                              float* sum, unsigned* mx, unsigned* mn, float* cnt, int n) {
  long t = (long)blockIdx.x * 256 + threadIdx.x;
  int q = (int)(t & 31) * 4;
  long r0 = (t >> 5) * 8;
  if (r0 >= n) return;
  int gcur = -1;
  float s0 = 0, s1 = 0, s2 = 0, s3 = 0, cc = 0;
  float x0 = 0, x1 = 0, x2 = 0, x3 = 0;
  float n0 = 0, n1 = 0, n2 = 0, n3 = 0;
  for (int k = 0; k < 8; ++k) {
    long r = r0 + k;
    if (r >= n) break;
    int g = gidx[r];
    float4 v = *(const float4*)&X[r * cH + q];
    if (g != gcur) {
      if (gcur >= 0) {
        long b = (long)gcur * cH + q;
        atomicAdd(&sum[b + 0], s0); atomicAdd(&sum[b + 1], s1);
        atomicAdd(&sum[b + 2], s2); atomicAdd(&sum[b + 3], s3);
        atomicMax(&mx[b + 0], fmap(x0)); atomicMax(&mx[b + 1], fmap(x1));
        atomicMax(&mx[b + 2], fmap(x2)); atomicMax(&mx[b + 3], fmap(x3));
        atomicMin(&mn[b + 0], fmap(n0)); atomicMin(&mn[b + 1], fmap(n1));
        atomicMin(&mn[b + 2], fmap(n2)); atomicMin(&mn[b + 3], fmap(n3));
        if (q == 0) atomicAdd(&cnt[gcur], cc);
      }
      gcur = g;
      s0 = v.x; s1 = v.y; s2 = v.z; s3 = v.w;
      x0 = v.x; x1 = v.y; x2 = v.z; x3 = v.w;
      n0 = v.x; n1 = v.y; n2 = v.z; n3 = v.w;
      cc = 1.f;
    } else {
      s0 += v.x; s1 += v.y; s2 += v.z; s3 += v.w;
      x0 = fmaxf(x0, v.x); x1 = fmaxf(x1, v.y); x2 = fmaxf(x2, v.z); x3 = fmaxf(x3, v.w);
      n0 = fminf(n0, v.x); n1 = fminf(n1, v.y); n2 = fminf(n2, v.z); n3 = fminf(n3, v.w);
      cc += 1.f;
    }
  }
  if (gcur >= 0) {
    long b = (long)gcur * cH + q;
    atomicAdd(&sum[b + 0], s0); atomicAdd(&sum[b + 1], s1);
    atomicAdd(&sum[b + 2], s2); atomicAdd(&sum[b + 3], s3);
    atomicMax(&mx[b + 0], fmap(x0)); atomicMax(&mx[b + 1], fmap(x1));
    atomicMax(&mx[b + 2], fmap(x2)); atomicMax(&mx[b + 3], fmap(x3));
    atomicMin(&mn[b + 0], fmap(n0)); atomicMin(&mn[b + 1], fmap(n1));
    atomicMin(&mn[b + 2], fmap(n2)); atomicMin(&mn[b + 3], fmap(n3));
    if (q == 0) atomicAdd(&cnt[gcur], cc);
  }
}

// ---------------- final MLP per graph (builds pooled vector from stats) ----------------
__global__ __launch_bounds__(128) void mlp_k(
    const char* __restrict__ ST, size_t stride,
    const float* __restrict__ f0w, const float* __restrict__ f0b,
    const float* __restrict__ f0g, const float* __restrict__ f0bb,
    const float* __restrict__ f1w, const float* __restrict__ f1b,
    const float* __restrict__ f1g, const float* __restrict__ f1bb,
    const float* __restrict__ fow, const float* __restrict__ fob,
    float* __restrict__ out) {
  __shared__ float hin[1152];
  __shared__ float red[8];
  int g = blockIdx.x, tid = threadIdx.x;
  // build pooled vector [mn0,mx0,mean0, mn1,mx1,mean1, mn2,mx2,mean2] directly
  #pragma unroll
  for (int p = 0; p < 3; ++p) {
    const char* b = ST + (size_t)p * stride;
    const float* sum = (const float*)b;
    const unsigned* mx = (const unsigned*)(b + (size_t)cG * cH * 4);
    const unsigned* mn = (const unsigned*)(b + (size_t)cG * cH * 8);
    const float* cnt = (const float*)(b + (size_t)cG * cH * 12);
    int idx = g * cH + tid;
    float ct = cnt[g];
    float mean = sum[idx] / fmaxf(ct, 1.f);
    float mxv = (ct > 0.f) ? funmap(mx[idx]) : 0.f;
    float mnv = (ct > 0.f) ? funmap(mn[idx]) : 0.f;
    hin[p * 384 + tid] = mnv;
    hin[p * 384 + 128 + tid] = mxv;
    hin[p * 384 + 256 + tid] = mean;
  }
  __syncthreads();
  float acc = f0b[tid];
  {
    const float* wr = f0w + (long)tid * 1152;
    for (int k = 0; k < 1152; k += 4) {
      float4 w4 = *(const float4*)(wr + k);
      float4 h4 = *(const float4*)&hin[k];
      acc = fmaf(h4.x, w4.x, acc);
      acc = fmaf(h4.y, w4.y, acc);
      acc = fmaf(h4.z, w4.z, acc);
      acc = fmaf(h4.w, w4.w, acc);
    }
  }
  float s = acc, s2 = acc * acc;
  #pragma unroll
  for (int m = 1; m < 64; m <<= 1) { s += __shfl_xor(s, m); s2 += __shfl_xor(s2, m); }
  if ((tid & 63) == 0) { red[tid >> 6] = s; red[4 + (tid >> 6)] = s2; }
  __syncthreads();
  s = red[0] + red[1]; s2 = red[4] + red[5];
  {
    float mean = s * (1.f / 128.f);
    float rstd = rsqrtf(s2 * (1.f / 128.f) - mean * mean + 1e-5f);
    float xn = (acc - mean) * rstd * f0g[tid] + f0bb[tid];
    float h0 = gelu_exact(xn);
    __syncthreads();
    hin[tid] = h0;
  }
  __syncthreads();
  acc = f1b[tid];
  {
    const float* wr = f1w + (long)tid * 128;
    for (int k = 0; k < 128; k += 4) {
      float4 w4 = *(const float4*)(wr + k);
      float4 h4 = *(const float4*)&hin[k];
      acc = fmaf(h4.x, w4.x, acc);
      acc = fmaf(h4.y, w4.y, acc);
      acc = fmaf(h4.z, w4.z, acc);
      acc = fmaf(h4.w, w4.w, acc);
    }
  }
  s = acc; s2 = acc * acc;
  #pragma unroll
  for (int m = 1; m < 64; m <<= 1) { s += __shfl_xor(s, m); s2 += __shfl_xor(s2, m); }
  __syncthreads();
  if ((tid & 63) == 0) { red[tid >> 6] = s; red[4 + (tid >> 6)] = s2; }
  __syncthreads();
  s = red[0] + red[1]; s2 = red[4] + red[5];
  float h1;
  {
    float mean = s * (1.f / 128.f);
    float rstd = rsqrtf(s2 * (1.f / 128.f) - mean * mean + 1e-5f);
    float xn = (acc - mean) * rstd * f1g[tid] + f1bb[tid];
    h1 = gelu_exact(xn);
  }
  float p = h1 * fow[tid];
  #pragma unroll
  for (int m = 1; m < 64; m <<= 1) p += __shfl_xor(p, m);
  __syncthreads();
  if ((tid & 63) == 0) red[tid >> 6] = p;
  __syncthreads();
  if (tid == 0) out[g] = red[0] + red[1] + fob[0];
}

// ---------------- launcher ----------------
extern "C" void kernel_launch(void* const* d_in, const int* in_sizes, int n_in,
                              void* d_out, int out_size, void* d_ws, size_t ws_size,
                              hipStream_t stream) {
  const float* x     = (const float*)d_in[0];
  const float* ea    = (const float*)d_in[1];
  const int*   ei    = (const int*)d_in[2];
  const int*   ue    = (const int*)d_in[3];
  const int*   batch = (const int*)d_in[4];
  const int*   l2nm  = (const int*)d_in[5];
  const int*   l2ei  = (const int*)d_in[6];
  const float* lew   = (const float*)d_in[8];
  const float* leb   = (const float*)d_in[9];
  const float* g1w   = (const float*)d_in[10];
  const float* g1b   = (const float*)d_in[11];
  const float* g2w   = (const float*)d_in[12];
  const float* g2b   = (const float*)d_in[13];
  const float* tinw  = (const float*)d_in[14];
  const float* tinb  = (const float*)d_in[15];
  const float* toutw = (const float*)d_in[16];
  const float* toutb = (const float*)d_in[17];
  const float* tl1g  = (const float*)d_in[18];
  const float* tl1b  = (const float*)d_in[19];
  const float* tl2g  = (const float*)d_in[20];
  const float* tl2b  = (const float*)d_in[21];
  const float* tf1w  = (const float*)d_in[22];
  const float* tf1b  = (const float*)d_in[23];
  const float* tf2w  = (const float*)d_in[24];
  const float* tf2b  = (const float*)d_in[25];
  const float* f0w   = (const float*)d_in[26];
  const float* f0b   = (const float*)d_in[27];
  const float* f0g   = (const float*)d_in[28];
  const float* f0bb  = (const float*)d_in[29];
  const float* f1w   = (const float*)d_in[30];
  const float* f1b   = (const float*)d_in[31];
  const float* f1g   = (const float*)d_in[32];
  const float* f1bb  = (const float*)d_in[33];
  const float* fow   = (const float*)d_in[34];
  const float* fob   = (const float*)d_in[35];
  float* out = (float*)d_out;

  char* ws = (char*)d_ws;
  size_t off = 0;
  float* H1  = (float*)(ws + off);  off += (size_t)cL2 * cH * 4;
  float* H0  = (float*)(ws + off);  off += (size_t)cL2 * cH * 4;
  float* XW  = (float*)(ws + off);  off += (size_t)cL2 * cH * 4;
  float* DEG = (float*)(ws + off);  off += (size_t)cL2 * 4;
  int*   L2B = (int*)(ws + off);    off += (size_t)cL2 * 4;
  int*   CNT = (int*)(ws + off);    off += (size_t)cL2 * 4;
  char*  ST  = ws + off;            off += 3 * ((size_t)cG * cH * 4 * 3 + cG * 4);
  int*   CSR1 = (int*)(ws + off);   off += (size_t)cN * CAP1 * 4;
  int*   CSR2 = (int*)(ws + off);   off += (size_t)cL2 * CAP2 * 4;
  // split-bf16 weight buffers
  unsigned short* WinH  = (unsigned short*)(ws + off); off += (size_t)cNL * 384 * 128 * 2;
  unsigned short* WinL  = (unsigned short*)(ws + off); off += (size_t)cNL * 384 * 128 * 2;
  unsigned short* WoutH = (unsigned short*)(ws + off); off += (size_t)cNL * 128 * 128 * 2;
  unsigned short* WoutL = (unsigned short*)(ws + off); off += (size_t)cNL * 128 * 128 * 2;
  unsigned short* Wf1H  = (unsigned short*)(ws + off); off += (size_t)cNL * 256 * 128 * 2;
  unsigned short* Wf1L  = (unsigned short*)(ws + off); off += (size_t)cNL * 256 * 128 * 2;
  unsigned short* Wf2H  = (unsigned short*)(ws + off); off += (size_t)cNL * 128 * 256 * 2;
  unsigned short* Wf2L  = (unsigned short*)(ws + off); off += (size_t)cNL * 128 * 256 * 2;

  size_t st_stride = (size_t)cG * cH * 4 * 3 + cG * 4;
  auto stat = [&](int p) {
    char* b = ST + p * st_stride;
    struct S { float* sum; unsigned* mx; unsigned* mn; float* cnt; } s;
    s.sum = (float*)b;
    s.mx  = (unsigned*)(b + (size_t)cG * cH * 4);
    s.mn  = (unsigned*)(b + (size_t)cG * cH * 8);
    s.cnt = (float*)(b + (size_t)cG * cH * 12);
    return s;
  };
  auto s0 = stat(0), s1 = stat(1), s2 = stat(2);

  // 0) split transformer weights into bf16 hi/lo; init all pool stats
  split_w_k<<<(cNL * 384 * 128 + 255) / 256, 256, 0, stream>>>(tinw, WinH, WinL, cNL * 384 * 128);
  split_w_k<<<(cNL * 128 * 128 + 255) / 256, 256, 0, stream>>>(toutw, WoutH, WoutL, cNL * 128 * 128);
  split_w_k<<<(cNL * 256 * 128 + 255) / 256, 256, 0, stream>>>(tf1w, Wf1H, Wf1L, cNL * 256 * 128);
  split_w_k<<<(cNL * 128 * 256 + 255) / 256, 256, 0, stream>>>(tf2w, Wf2H, Wf2L, cNL * 128 * 256);
  init_stats3_k<<<(cG * cH + 255) / 256, 256, 0, stream>>>(ST, st_stride);

  // 1) GCN1 -> H0 (CSR gather; dinv derived from CSR counts)
  gemm128_k<<<(cN + 127) / 128, 256, 0, stream>>>(x, g1w, XW, cN);
  fill_k<<<(cN + 255) / 256, 256, 0, stream>>>((float*)CNT, 0.0f, cN);   // int 0
  csr_fill_k<<<(cE + 255) / 256, 256, 0, stream>>>(ei, CNT, CSR1, CAP1, cE);
  cnt_to_dinv_k<<<(cN + 255) / 256, 256, 0, stream>>>(CNT, DEG, cN);
  gcn_gather_k<1><<<(cN + 3) / 4, 256, 0, stream>>>(XW, DEG, CSR1, CNT, g1b, H0,
      nullptr, nullptr, nullptr, nullptr, nullptr, cN, CAP1);

  // 2) fused MFMA transformer encoder -> H1 (+pool H1, +L2B)
  hipFuncSetAttribute(reinterpret_cast<const void*>(encoder_k),
                      hipFuncAttributeMaxDynamicSharedMemorySize, 131072);
  encoder_k<<<cL2 / ESETS, 512, SMEM_SZ, stream>>>(H0, ea, lew, leb, ue, l2nm, batch,
      WinH, WinL, tinb, WoutH, WoutL, toutb, tl1g, tl1b, tl2g, tl2b,
      Wf1H, Wf1L, tf1b, Wf2H, Wf2L, tf2b, H1,
      s1.sum, s1.mx, s1.mn, s1.cnt, L2B);

  // 3) pool H0 (sorted batch -> segmented)
  pool_sorted_k<<<(int)((((long)(cN + 7) / 8) * 32 + 255) / 256), 256, 0, stream>>>(
      H0, batch, s0.sum, s0.mx, s0.mn, s0.cnt, cN);

  // 4) GCN2 (CSR gather, relu+pool fused; H2 never materialized)
  gemm128_k<<<(cL2 + 127) / 128, 256, 0, stream>>>(H1, g2w, XW, cL2);
  fill_k<<<(cL2 + 255) / 256, 256, 0, stream>>>((float*)CNT, 0.0f, cL2);
  csr_fill_k<<<(cEL + 255) / 256, 256, 0, stream>>>(l2ei, CNT, CSR2, CAP2, cEL);
  cnt_to_dinv_k<<<(cL2 + 255) / 256, 256, 0, stream>>>(CNT, DEG, cL2);
  gcn_gather_k<0><<<(cL2 + 3) / 4, 256, 0, stream>>>(XW, DEG, CSR2, CNT, g2b, nullptr,
      L2B, s2.sum, s2.mx, s2.mn, s2.cnt, cL2, CAP2);

  // 5) final MLP -> out[512] (pool finalize fused into prologue)
  mlp_k<<<cG, 128, 0, stream>>>(ST, st_stride, f0w, f0b, f0g, f0bb, f1w, f1b, f1g, f1bb, fow, fob, out);
}